// Round 2
// baseline (314.080 us; speedup 1.0000x reference)
//
#include <hip/hip_runtime.h>

#define BB 64
#define TT 16384
#define EE 512

typedef _Float16 half8 __attribute__((ext_vector_type(8)));
typedef float floatx4 __attribute__((ext_vector_type(4)));

static __device__ __forceinline__ half8 cvt_half8(float4 a, float4 b) {
  half8 h;
  h[0] = (_Float16)a.x; h[1] = (_Float16)a.y; h[2] = (_Float16)a.z; h[3] = (_Float16)a.w;
  h[4] = (_Float16)b.x; h[5] = (_Float16)b.y; h[6] = (_Float16)b.z; h[7] = (_Float16)b.w;
  return h;
}

// ---------------------------------------------------------------------------
// Zero the split-K fp32 accumulators. MUST be a kernel (not hipMemsetAsync):
// hipMemsetAsync is not reliably captured into the timing graph, and the
// harness does not re-poison d_ws between graph replays -> atomicAdd results
// accumulate across replays (observed: absmax 4.28 after timing, 0.03 on the
// fresh first call). 352*256 threads * float4 = 1,441,792 B exactly.
// ---------------------------------------------------------------------------
__global__ __launch_bounds__(256) void zero_ws(float4* __restrict__ p) {
  p[blockIdx.x * 256 + threadIdx.x] = (float4){0.f, 0.f, 0.f, 0.f};
}

// ---------------------------------------------------------------------------
// Stage 1: Xq[r][e] = sum_t x_row(r)[t] * W[e][t]   (split-K, fp16 MFMA)
// A rows map to x rows (b*7 + chan_base + j), r = b*chan_per_b + j.
// For the K/V pass, columns [0,512) use Wa (=Wk) and [512,1024) use Wb (=Wv).
// Partial sums accumulated with fp32 atomicAdd (output pre-zeroed by zero_ws).
// ---------------------------------------------------------------------------
__global__ __launch_bounds__(256) void proj_gemm(
    const float* __restrict__ x, const float* __restrict__ Wa,
    const float* __restrict__ Wb, float* __restrict__ outC,
    int chan_base, int chan_per_b, int ldout)
{
  __shared__ _Float16 As[64][40];    // [m][k], +8 pad
  __shared__ _Float16 Bs[128][40];   // [n][k]
  const int t = threadIdx.x;
  const int wave = t >> 6, lane = t & 63;
  const int quad = lane >> 4, l16 = lane & 15;
  const int mtile = blockIdx.y, ntile = blockIdx.x;
  const int k0 = blockIdx.z << 10;   // split-K chunk of 1024

  // A staging: thread -> (row 0..63, 8-float chunk)
  const int arow = t >> 2, akk = (t & 3) << 3;
  const int r = mtile * 64 + arow;
  const int bidx = r / chan_per_b;
  const int j = r - bidx * chan_per_b;
  const float* aptr = x + (size_t)(bidx * 7 + chan_base + j) * TT + k0 + akk;

  // B staging: thread -> (col 0..127, 16-float chunk)
  const int brow = t >> 1, bkk = (t & 1) << 4;
  const int ncol = ntile * 128 + brow;
  const float* wsrc = (ncol < EE) ? Wa : Wb;
  const float* bptr = wsrc + (size_t)(ncol & (EE - 1)) * TT + k0 + bkk;

  floatx4 acc[4][2];
  for (int rt = 0; rt < 4; ++rt)
    for (int ct = 0; ct < 2; ++ct)
      acc[rt][ct] = (floatx4){0.f, 0.f, 0.f, 0.f};

  for (int kt = 0; kt < 32; ++kt) {
    __syncthreads();
    float4 a0 = *(const float4*)aptr;
    float4 a1 = *(const float4*)(aptr + 4);
    float4 b0 = *(const float4*)bptr;
    float4 b1 = *(const float4*)(bptr + 4);
    float4 b2 = *(const float4*)(bptr + 8);
    float4 b3 = *(const float4*)(bptr + 12);
    *(half8*)&As[arow][akk]     = cvt_half8(a0, a1);
    *(half8*)&Bs[brow][bkk]     = cvt_half8(b0, b1);
    *(half8*)&Bs[brow][bkk + 8] = cvt_half8(b2, b3);
    aptr += 32; bptr += 32;
    __syncthreads();
    // wave w owns cols [32w, 32w+32)
    half8 bf0 = *(const half8*)&Bs[wave * 32 + l16][quad * 8];
    half8 bf1 = *(const half8*)&Bs[wave * 32 + 16 + l16][quad * 8];
#pragma unroll
    for (int rt = 0; rt < 4; ++rt) {
      half8 af = *(const half8*)&As[rt * 16 + l16][quad * 8];
      acc[rt][0] = __builtin_amdgcn_mfma_f32_16x16x32_f16(af, bf0, acc[rt][0], 0, 0, 0);
      acc[rt][1] = __builtin_amdgcn_mfma_f32_16x16x32_f16(af, bf1, acc[rt][1], 0, 0, 0);
    }
  }
  // C/D layout: col = lane&15, row = quad*4 + reg
#pragma unroll
  for (int rt = 0; rt < 4; ++rt) {
#pragma unroll
    for (int ct = 0; ct < 2; ++ct) {
      const int gr = mtile * 64 + rt * 16 + quad * 4;
      const int gc = ntile * 128 + wave * 32 + ct * 16 + l16;
#pragma unroll
      for (int rg = 0; rg < 4; ++rg)
        atomicAdd(&outC[(size_t)(gr + rg) * ldout + gc], acc[rt][ct][rg]);
    }
  }
}

// ---------------------------------------------------------------------------
// Stage 2: per (batch, 64-wide e-chunk): build K(16x512), VW(3x512), Q(16x64)
// in LDS, then per e-row: S = 0.25*Q^T K, softmax over f, u[o,e]=P·VW[o]/den.
// VW[o][f] = sum_j (W3·W2)[o][j]·Xv[j][f] + (sum_c W3[o][c])·bv[f].
// ---------------------------------------------------------------------------
__global__ __launch_bounds__(256) void attn_mid(
    const float* __restrict__ Xq, const float* __restrict__ Xkv,
    const float* __restrict__ W1, const float* __restrict__ W2,
    const float* __restrict__ W3,
    const float* __restrict__ bq, const float* __restrict__ bk,
    const float* __restrict__ bv, _Float16* __restrict__ U)
{
  __shared__ float Ks[16][512];
  __shared__ float VW[3][512];
  __shared__ float Qs[16][64];
  __shared__ float Xs[4][512];
  __shared__ float W1s[48], W2s[64], W3s[48], W32s[12], w3sum[3];
  const int t = threadIdx.x;
  const int b = blockIdx.y;
  const int e0 = blockIdx.x * 64;

  if (t < 48) W1s[t] = W1[t];
  if (t >= 64 && t < 128) W2s[t - 64] = W2[t - 64];
  if (t >= 128 && t < 176) W3s[t - 128] = W3[t - 128];
  __syncthreads();
  if (t < 12) {                       // W32[o][j] = sum_c W3[o][c]*W2[c][j]
    const int o = t >> 2, jj = t & 3;
    float s = 0.f;
    for (int c = 0; c < 16; ++c) s += W3s[o * 16 + c] * W2s[c * 4 + jj];
    W32s[t] = s;
  }
  if (t >= 16 && t < 19) {
    const int o = t - 16;
    float s = 0.f;
    for (int c = 0; c < 16; ++c) s += W3s[o * 16 + c];
    w3sum[o] = s;
  }
  // stage Xk, build K
  for (int i = t; i < 2048; i += 256) {
    const int jj = i >> 9, f = i & 511;
    Xs[jj][f] = Xkv[(size_t)(b * 4 + jj) * 1024 + f];
  }
  __syncthreads();
  for (int i = t; i < 8192; i += 256) {
    const int c = i >> 9, f = i & 511;
    float s = bk[f];
#pragma unroll
    for (int jj = 0; jj < 4; ++jj) s += W2s[c * 4 + jj] * Xs[jj][f];
    Ks[c][f] = s;
  }
  __syncthreads();
  // stage Xv, build VW
  for (int i = t; i < 2048; i += 256) {
    const int jj = i >> 9, f = i & 511;
    Xs[jj][f] = Xkv[(size_t)(b * 4 + jj) * 1024 + 512 + f];
  }
  __syncthreads();
  for (int i = t; i < 1536; i += 256) {
    const int o = i >> 9, f = i & 511;
    float s = w3sum[o] * bv[f];
#pragma unroll
    for (int jj = 0; jj < 4; ++jj) s += W32s[o * 4 + jj] * Xs[jj][f];
    VW[o][f] = s;
  }
  // build Q for this e-chunk
  for (int i = t; i < 1024; i += 256) {
    const int c = i >> 6, el = i & 63;
    float s = bq[e0 + el];
#pragma unroll
    for (int jj = 0; jj < 3; ++jj)
      s += W1s[c * 3 + jj] * Xq[(size_t)(b * 3 + jj) * 512 + e0 + el];
    Qs[c][el] = s;
  }
  __syncthreads();

  const int wave = t >> 6, lane = t & 63;
  // hoist VW strip (f = lane*8 .. +8) into registers
  float vwr[3][8];
#pragma unroll
  for (int o = 0; o < 3; ++o) {
    float4 va = *(const float4*)&VW[o][lane * 8];
    float4 vb = *(const float4*)&VW[o][lane * 8 + 4];
    vwr[o][0] = va.x; vwr[o][1] = va.y; vwr[o][2] = va.z; vwr[o][3] = va.w;
    vwr[o][4] = vb.x; vwr[o][5] = vb.y; vwr[o][6] = vb.z; vwr[o][7] = vb.w;
  }

  for (int g = 0; g < 4; ++g) {       // 4 groups of 4 e-rows per wave
    const int el0 = wave * 16 + g * 4;
    float s[4][8];
#pragma unroll
    for (int e = 0; e < 4; ++e)
#pragma unroll
      for (int i = 0; i < 8; ++i) s[e][i] = 0.f;
#pragma unroll
    for (int c = 0; c < 16; ++c) {
      float4 k0 = *(const float4*)&Ks[c][lane * 8];
      float4 k1 = *(const float4*)&Ks[c][lane * 8 + 4];
      float4 qv = *(const float4*)&Qs[c][el0];
      float qa[4] = {qv.x, qv.y, qv.z, qv.w};
#pragma unroll
      for (int e = 0; e < 4; ++e) {
        const float q = qa[e];
        s[e][0] += q * k0.x; s[e][1] += q * k0.y; s[e][2] += q * k0.z; s[e][3] += q * k0.w;
        s[e][4] += q * k1.x; s[e][5] += q * k1.y; s[e][6] += q * k1.z; s[e][7] += q * k1.w;
      }
    }
#pragma unroll
    for (int e = 0; e < 4; ++e) {
      float mx = s[e][0];
#pragma unroll
      for (int i = 1; i < 8; ++i) mx = fmaxf(mx, s[e][i]);
#pragma unroll
      for (int off = 32; off; off >>= 1) mx = fmaxf(mx, __shfl_xor(mx, off));
      float p[8], sum = 0.f;
#pragma unroll
      for (int i = 0; i < 8; ++i) { p[i] = __expf(0.25f * (s[e][i] - mx)); sum += p[i]; }
      float u0 = 0.f, u1 = 0.f, u2 = 0.f;
#pragma unroll
      for (int i = 0; i < 8; ++i) {
        u0 += p[i] * vwr[0][i];
        u1 += p[i] * vwr[1][i];
        u2 += p[i] * vwr[2][i];
      }
#pragma unroll
      for (int off = 32; off; off >>= 1) {
        sum += __shfl_xor(sum, off);
        u0  += __shfl_xor(u0, off);
        u1  += __shfl_xor(u1, off);
        u2  += __shfl_xor(u2, off);
      }
      if (lane == 0) {
        const float inv = 1.0f / sum;
        const size_t base = (size_t)b * 3 * 512 + (e0 + el0 + e);
        U[base]        = (_Float16)(u0 * inv);
        U[base + 512]  = (_Float16)(u1 * inv);
        U[base + 1024] = (_Float16)(u2 * inv);
      }
    }
  }
}

// ---------------------------------------------------------------------------
// Stage 3: out[r][t] = sum_e U[r][e]*Wo[t][e] + x[(b*7+o)][t] + w3sum[o]*bo[t]
// r = b*3 + o;  M=192, N=16384, K=512. fp16 MFMA.
// ---------------------------------------------------------------------------
__global__ __launch_bounds__(256) void out_gemm(
    const _Float16* __restrict__ U, const float* __restrict__ Wo,
    const float* __restrict__ x, const float* __restrict__ bo,
    const float* __restrict__ W3, float* __restrict__ outY)
{
  __shared__ _Float16 As[64][40];
  __shared__ _Float16 Bs[128][40];
  __shared__ float w3sh[3];
  const int t = threadIdx.x;
  const int wave = t >> 6, lane = t & 63;
  const int quad = lane >> 4, l16 = lane & 15;
  const int mtile = blockIdx.y, ntile = blockIdx.x;
  if (t < 3) {
    float s = 0.f;
    for (int c = 0; c < 16; ++c) s += W3[t * 16 + c];
    w3sh[t] = s;
  }
  const int arow = t >> 2, akk = (t & 3) << 3;
  const _Float16* aptr = U + (size_t)(mtile * 64 + arow) * EE + akk;
  const int brow = t >> 1, bkk = (t & 1) << 4;
  const float* bptr = Wo + (size_t)(ntile * 128 + brow) * EE + bkk;

  floatx4 acc[4][2];
  for (int rt = 0; rt < 4; ++rt)
    for (int ct = 0; ct < 2; ++ct)
      acc[rt][ct] = (floatx4){0.f, 0.f, 0.f, 0.f};

  for (int kt = 0; kt < 16; ++kt) {
    __syncthreads();
    half8 av = *(const half8*)aptr;
    float4 b0 = *(const float4*)bptr;
    float4 b1 = *(const float4*)(bptr + 4);
    float4 b2 = *(const float4*)(bptr + 8);
    float4 b3 = *(const float4*)(bptr + 12);
    *(half8*)&As[arow][akk]     = av;
    *(half8*)&Bs[brow][bkk]     = cvt_half8(b0, b1);
    *(half8*)&Bs[brow][bkk + 8] = cvt_half8(b2, b3);
    aptr += 32; bptr += 32;
    __syncthreads();
    half8 bf0 = *(const half8*)&Bs[wave * 32 + l16][quad * 8];
    half8 bf1 = *(const half8*)&Bs[wave * 32 + 16 + l16][quad * 8];
#pragma unroll
    for (int rt = 0; rt < 4; ++rt) {
      half8 af = *(const half8*)&As[rt * 16 + l16][quad * 8];
      acc[rt][0] = __builtin_amdgcn_mfma_f32_16x16x32_f16(af, bf0, acc[rt][0], 0, 0, 0);
      acc[rt][1] = __builtin_amdgcn_mfma_f32_16x16x32_f16(af, bf1, acc[rt][1], 0, 0, 0);
    }
  }
#pragma unroll
  for (int rt = 0; rt < 4; ++rt) {
#pragma unroll
    for (int ct = 0; ct < 2; ++ct) {
      const int gr = mtile * 64 + rt * 16 + quad * 4;
      const int tc = ntile * 128 + wave * 32 + ct * 16 + l16;
      const float bot = bo[tc];
#pragma unroll
      for (int rg = 0; rg < 4; ++rg) {
        const int rr = gr + rg;
        const int bb = rr / 3, oo = rr - bb * 3;
        const float v = acc[rt][ct][rg]
                      + x[(size_t)(bb * 7 + oo) * TT + tc]
                      + w3sh[oo] * bot;
        outY[(size_t)rr * TT + tc] = v;
      }
    }
  }
}

extern "C" void kernel_launch(void* const* d_in, const int* in_sizes, int n_in,
                              void* d_out, int out_size, void* d_ws, size_t ws_size,
                              hipStream_t stream) {
  const float* x  = (const float*)d_in[0];
  const float* W1 = (const float*)d_in[1];
  const float* W2 = (const float*)d_in[2];
  const float* Wq = (const float*)d_in[3];
  const float* bq = (const float*)d_in[4];
  const float* Wk = (const float*)d_in[5];
  const float* bk = (const float*)d_in[6];
  const float* Wv = (const float*)d_in[7];
  const float* bv = (const float*)d_in[8];
  const float* Wo = (const float*)d_in[9];
  const float* bo = (const float*)d_in[10];
  const float* W3 = (const float*)d_in[11];
  float* out = (float*)d_out;

  char* ws = (char*)d_ws;
  float* Xq      = (float*)ws;                  // 192*512  fp32 = 393216 B
  float* Xkv     = (float*)(ws + 393216);       // 256*1024 fp32 = 1048576 B
  _Float16* U    = (_Float16*)(ws + 1441792);   // 192*512  fp16 = 196608 B

  // zero the split-K accumulators (kernel, NOT hipMemsetAsync: memset is not
  // reliably captured into the timing graph -> cross-replay accumulation)
  zero_ws<<<dim3(352), 256, 0, stream>>>((float4*)ws);

  // Xq: 3 p-channels  x Wq   -> (192 x 512)
  proj_gemm<<<dim3(4, 3, 16), 256, 0, stream>>>(x, Wq, Wq, Xq, 0, 3, 512);
  // Xkv: 4 c-channels x [Wk|Wv] -> (256 x 1024)
  proj_gemm<<<dim3(8, 4, 16), 256, 0, stream>>>(x, Wk, Wv, Xkv, 3, 4, 1024);
  // attention middle -> U (192 x 512 fp16)
  attn_mid<<<dim3(8, BB), 256, 0, stream>>>(Xq, Xkv, W1, W2, W3, bq, bk, bv, U);
  // final projection + residual + bias
  out_gemm<<<dim3(128, 3), 256, 0, stream>>>(U, Wo, x, bo, W3, out);
}

// Round 3
// 274.095 us; speedup vs baseline: 1.1459x; 1.1459x over previous
//
#include <hip/hip_runtime.h>

#define BB 64
#define TT 16384
#define EE 512

typedef _Float16 half8 __attribute__((ext_vector_type(8)));
typedef float floatx4 __attribute__((ext_vector_type(4)));

static __device__ __forceinline__ half8 cvt_half8(float4 a, float4 b) {
  half8 h;
  h[0] = (_Float16)a.x; h[1] = (_Float16)a.y; h[2] = (_Float16)a.z; h[3] = (_Float16)a.w;
  h[4] = (_Float16)b.x; h[5] = (_Float16)b.y; h[6] = (_Float16)b.z; h[7] = (_Float16)b.w;
  return h;
}

// ---------------------------------------------------------------------------
// Zero the split-K fp32 accumulators. MUST be a kernel (not hipMemsetAsync):
// memset nodes are not reliably captured into the timing graph and d_ws is
// not re-poisoned between replays -> cross-replay accumulation (R1 bug).
// ---------------------------------------------------------------------------
__global__ __launch_bounds__(256) void zero_ws(float4* __restrict__ p) {
  p[blockIdx.x * 256 + threadIdx.x] = (float4){0.f, 0.f, 0.f, 0.f};
}

// ---------------------------------------------------------------------------
// Stage 1 (merged): both projections in ONE launch for occupancy.
//   tiles 0..11 : Xq  (3 mtiles x 4 ntiles), rows = (b,3 p-chans) x Wq
//   tiles 12..43: Xkv (4 mtiles x 8 ntiles), rows = (b,4 c-chans) x [Wk|Wv]
// blockIdx.y = split-K chunk (32 chunks of 512). fp16 MFMA, fp32 atomicAdd.
// Register-prefetch double buffering: next tile's global loads issue before
// the MFMAs of the current tile -> HBM latency overlaps compute.
// R2 counters (pre-fix): 22% HBM, 4.6% MFMA, 20% occ -> latency-bound.
// ---------------------------------------------------------------------------
__global__ __launch_bounds__(256) void proj_gemm(
    const float* __restrict__ x, const float* __restrict__ Wq,
    const float* __restrict__ Wk, const float* __restrict__ Wv,
    float* __restrict__ Xq, float* __restrict__ Xkv)
{
  __shared__ _Float16 As[64][40];    // [m][k], +8 pad
  __shared__ _Float16 Bs[128][40];   // [n][k]
  const int t = threadIdx.x;
  const int wave = t >> 6, lane = t & 63;
  const int quad = lane >> 4, l16 = lane & 15;

  const int tile = blockIdx.x;
  int mtile, ntile, chan_base, cpb, ldout;
  const float *Wa, *Wb;
  float* outC;
  if (tile < 12) {
    mtile = tile >> 2; ntile = tile & 3;
    chan_base = 0; cpb = 3; ldout = 512;
    Wa = Wq; Wb = Wq; outC = Xq;
  } else {
    const int t2 = tile - 12;
    mtile = t2 >> 3; ntile = t2 & 7;
    chan_base = 3; cpb = 4; ldout = 1024;
    Wa = Wk; Wb = Wv; outC = Xkv;
  }
  const int k0 = blockIdx.y << 9;    // split-K chunk of 512

  // A staging: thread -> (row 0..63, 8-float chunk)
  const int arow = t >> 2, akk = (t & 3) << 3;
  const int r = mtile * 64 + arow;
  const int bidx = r / cpb;
  const int j = r - bidx * cpb;
  const float* aptr = x + (size_t)(bidx * 7 + chan_base + j) * TT + k0 + akk;

  // B staging: thread -> (col 0..127, 16-float chunk)
  const int brow = t >> 1, bkk = (t & 1) << 4;
  const int ncol = ntile * 128 + brow;
  const float* wsrc = (ncol < EE) ? Wa : Wb;
  const float* bptr = wsrc + (size_t)(ncol & (EE - 1)) * TT + k0 + bkk;

  floatx4 acc[4][2];
  for (int rt = 0; rt < 4; ++rt)
    for (int ct = 0; ct < 2; ++ct)
      acc[rt][ct] = (floatx4){0.f, 0.f, 0.f, 0.f};

  // prefetch k-tile 0
  float4 a0 = *(const float4*)aptr;
  float4 a1 = *(const float4*)(aptr + 4);
  float4 b0 = *(const float4*)bptr;
  float4 b1 = *(const float4*)(bptr + 4);
  float4 b2 = *(const float4*)(bptr + 8);
  float4 b3 = *(const float4*)(bptr + 12);

  for (int kt = 0; kt < 16; ++kt) {
    const half8 ha  = cvt_half8(a0, a1);
    const half8 hb0 = cvt_half8(b0, b1);
    const half8 hb1 = cvt_half8(b2, b3);
    __syncthreads();
    *(half8*)&As[arow][akk]     = ha;
    *(half8*)&Bs[brow][bkk]     = hb0;
    *(half8*)&Bs[brow][bkk + 8] = hb1;
    __syncthreads();
    if (kt < 15) {                   // issue next tile's loads NOW
      aptr += 32; bptr += 32;
      a0 = *(const float4*)aptr;
      a1 = *(const float4*)(aptr + 4);
      b0 = *(const float4*)bptr;
      b1 = *(const float4*)(bptr + 4);
      b2 = *(const float4*)(bptr + 8);
      b3 = *(const float4*)(bptr + 12);
    }
    // wave w owns cols [32w, 32w+32)
    half8 bf0 = *(const half8*)&Bs[wave * 32 + l16][quad * 8];
    half8 bf1 = *(const half8*)&Bs[wave * 32 + 16 + l16][quad * 8];
#pragma unroll
    for (int rt = 0; rt < 4; ++rt) {
      half8 af = *(const half8*)&As[rt * 16 + l16][quad * 8];
      acc[rt][0] = __builtin_amdgcn_mfma_f32_16x16x32_f16(af, bf0, acc[rt][0], 0, 0, 0);
      acc[rt][1] = __builtin_amdgcn_mfma_f32_16x16x32_f16(af, bf1, acc[rt][1], 0, 0, 0);
    }
  }
  // C/D layout: col = lane&15, row = quad*4 + reg
#pragma unroll
  for (int rt = 0; rt < 4; ++rt) {
#pragma unroll
    for (int ct = 0; ct < 2; ++ct) {
      const int gr = mtile * 64 + rt * 16 + quad * 4;
      const int gc = ntile * 128 + wave * 32 + ct * 16 + l16;
#pragma unroll
      for (int rg = 0; rg < 4; ++rg)
        atomicAdd(&outC[(size_t)(gr + rg) * ldout + gc], acc[rt][ct][rg]);
    }
  }
}

// ---------------------------------------------------------------------------
// Stage 2: per (batch, 64-wide e-chunk): build K(16x512), VW(3x512), Q(16x64)
// in LDS, then per e-row: S = 0.25*Q^T K, softmax over f, u[o,e]=P·VW[o]/den.
// (unchanged from R2 — verified correct, not in top-5)
// ---------------------------------------------------------------------------
__global__ __launch_bounds__(256) void attn_mid(
    const float* __restrict__ Xq, const float* __restrict__ Xkv,
    const float* __restrict__ W1, const float* __restrict__ W2,
    const float* __restrict__ W3,
    const float* __restrict__ bq, const float* __restrict__ bk,
    const float* __restrict__ bv, _Float16* __restrict__ U)
{
  __shared__ float Ks[16][512];
  __shared__ float VW[3][512];
  __shared__ float Qs[16][64];
  __shared__ float Xs[4][512];
  __shared__ float W1s[48], W2s[64], W3s[48], W32s[12], w3sum[3];
  const int t = threadIdx.x;
  const int b = blockIdx.y;
  const int e0 = blockIdx.x * 64;

  if (t < 48) W1s[t] = W1[t];
  if (t >= 64 && t < 128) W2s[t - 64] = W2[t - 64];
  if (t >= 128 && t < 176) W3s[t - 128] = W3[t - 128];
  __syncthreads();
  if (t < 12) {                       // W32[o][j] = sum_c W3[o][c]*W2[c][j]
    const int o = t >> 2, jj = t & 3;
    float s = 0.f;
    for (int c = 0; c < 16; ++c) s += W3s[o * 16 + c] * W2s[c * 4 + jj];
    W32s[t] = s;
  }
  if (t >= 16 && t < 19) {
    const int o = t - 16;
    float s = 0.f;
    for (int c = 0; c < 16; ++c) s += W3s[o * 16 + c];
    w3sum[o] = s;
  }
  // stage Xk, build K
  for (int i = t; i < 2048; i += 256) {
    const int jj = i >> 9, f = i & 511;
    Xs[jj][f] = Xkv[(size_t)(b * 4 + jj) * 1024 + f];
  }
  __syncthreads();
  for (int i = t; i < 8192; i += 256) {
    const int c = i >> 9, f = i & 511;
    float s = bk[f];
#pragma unroll
    for (int jj = 0; jj < 4; ++jj) s += W2s[c * 4 + jj] * Xs[jj][f];
    Ks[c][f] = s;
  }
  __syncthreads();
  // stage Xv, build VW
  for (int i = t; i < 2048; i += 256) {
    const int jj = i >> 9, f = i & 511;
    Xs[jj][f] = Xkv[(size_t)(b * 4 + jj) * 1024 + 512 + f];
  }
  __syncthreads();
  for (int i = t; i < 1536; i += 256) {
    const int o = i >> 9, f = i & 511;
    float s = w3sum[o] * bv[f];
#pragma unroll
    for (int jj = 0; jj < 4; ++jj) s += W32s[o * 4 + jj] * Xs[jj][f];
    VW[o][f] = s;
  }
  // build Q for this e-chunk
  for (int i = t; i < 1024; i += 256) {
    const int c = i >> 6, el = i & 63;
    float s = bq[e0 + el];
#pragma unroll
    for (int jj = 0; jj < 3; ++jj)
      s += W1s[c * 3 + jj] * Xq[(size_t)(b * 3 + jj) * 512 + e0 + el];
    Qs[c][el] = s;
  }
  __syncthreads();

  const int wave = t >> 6, lane = t & 63;
  float vwr[3][8];
#pragma unroll
  for (int o = 0; o < 3; ++o) {
    float4 va = *(const float4*)&VW[o][lane * 8];
    float4 vb = *(const float4*)&VW[o][lane * 8 + 4];
    vwr[o][0] = va.x; vwr[o][1] = va.y; vwr[o][2] = va.z; vwr[o][3] = va.w;
    vwr[o][4] = vb.x; vwr[o][5] = vb.y; vwr[o][6] = vb.z; vwr[o][7] = vb.w;
  }

  for (int g = 0; g < 4; ++g) {       // 4 groups of 4 e-rows per wave
    const int el0 = wave * 16 + g * 4;
    float s[4][8];
#pragma unroll
    for (int e = 0; e < 4; ++e)
#pragma unroll
      for (int i = 0; i < 8; ++i) s[e][i] = 0.f;
#pragma unroll
    for (int c = 0; c < 16; ++c) {
      float4 k0 = *(const float4*)&Ks[c][lane * 8];
      float4 k1 = *(const float4*)&Ks[c][lane * 8 + 4];
      float4 qv = *(const float4*)&Qs[c][el0];
      float qa[4] = {qv.x, qv.y, qv.z, qv.w};
#pragma unroll
      for (int e = 0; e < 4; ++e) {
        const float q = qa[e];
        s[e][0] += q * k0.x; s[e][1] += q * k0.y; s[e][2] += q * k0.z; s[e][3] += q * k0.w;
        s[e][4] += q * k1.x; s[e][5] += q * k1.y; s[e][6] += q * k1.z; s[e][7] += q * k1.w;
      }
    }
#pragma unroll
    for (int e = 0; e < 4; ++e) {
      float mx = s[e][0];
#pragma unroll
      for (int i = 1; i < 8; ++i) mx = fmaxf(mx, s[e][i]);
#pragma unroll
      for (int off = 32; off; off >>= 1) mx = fmaxf(mx, __shfl_xor(mx, off));
      float p[8], sum = 0.f;
#pragma unroll
      for (int i = 0; i < 8; ++i) { p[i] = __expf(0.25f * (s[e][i] - mx)); sum += p[i]; }
      float u0 = 0.f, u1 = 0.f, u2 = 0.f;
#pragma unroll
      for (int i = 0; i < 8; ++i) {
        u0 += p[i] * vwr[0][i];
        u1 += p[i] * vwr[1][i];
        u2 += p[i] * vwr[2][i];
      }
#pragma unroll
      for (int off = 32; off; off >>= 1) {
        sum += __shfl_xor(sum, off);
        u0  += __shfl_xor(u0, off);
        u1  += __shfl_xor(u1, off);
        u2  += __shfl_xor(u2, off);
      }
      if (lane == 0) {
        const float inv = 1.0f / sum;
        const size_t base = (size_t)b * 3 * 512 + (e0 + el0 + e);
        U[base]        = (_Float16)(u0 * inv);
        U[base + 512]  = (_Float16)(u1 * inv);
        U[base + 1024] = (_Float16)(u2 * inv);
      }
    }
  }
}

// ---------------------------------------------------------------------------
// Stage 3: out[r][t] = sum_e U[r][e]*Wo[t][e] + x[(b*7+o)][t] + w3sum[o]*bo[t]
// r = b*3 + o;  M=192, N=16384, K=512. fp16 MFMA.
// 64x64 tiles -> 768 blocks (3/CU, was 1.5/CU) + register prefetch.
// ---------------------------------------------------------------------------
__global__ __launch_bounds__(256) void out_gemm(
    const _Float16* __restrict__ U, const float* __restrict__ Wo,
    const float* __restrict__ x, const float* __restrict__ bo,
    const float* __restrict__ W3, float* __restrict__ outY)
{
  __shared__ _Float16 As[64][40];
  __shared__ _Float16 Bs[64][40];
  __shared__ float w3sh[3];
  const int t = threadIdx.x;
  const int wave = t >> 6, lane = t & 63;
  const int quad = lane >> 4, l16 = lane & 15;
  const int mtile = blockIdx.y, ntile = blockIdx.x;
  if (t < 3) {
    float s = 0.f;
    for (int c = 0; c < 16; ++c) s += W3[t * 16 + c];
    w3sh[t] = s;
  }
  // A: 64 rows x 32 k halfs; B: 64 cols x 32 k floats -> halfs
  const int arow = t >> 2, akk = (t & 3) << 3;
  const _Float16* aptr = U + (size_t)(mtile * 64 + arow) * EE + akk;
  const int brow = t >> 2, bkk = (t & 3) << 3;
  const float* bptr = Wo + (size_t)(ntile * 64 + brow) * EE + bkk;

  floatx4 acc[4];
  for (int rt = 0; rt < 4; ++rt) acc[rt] = (floatx4){0.f, 0.f, 0.f, 0.f};

  half8 av = *(const half8*)aptr;
  float4 b0 = *(const float4*)bptr;
  float4 b1 = *(const float4*)(bptr + 4);

  for (int kt = 0; kt < 16; ++kt) {
    const half8 hb = cvt_half8(b0, b1);
    const half8 ha = av;
    __syncthreads();
    *(half8*)&As[arow][akk] = ha;
    *(half8*)&Bs[brow][bkk] = hb;
    __syncthreads();
    if (kt < 15) {
      aptr += 32; bptr += 32;
      av = *(const half8*)aptr;
      b0 = *(const float4*)bptr;
      b1 = *(const float4*)(bptr + 4);
    }
    // wave w owns cols [16w, 16w+16)
    half8 bf = *(const half8*)&Bs[wave * 16 + l16][quad * 8];
#pragma unroll
    for (int rt = 0; rt < 4; ++rt) {
      half8 af = *(const half8*)&As[rt * 16 + l16][quad * 8];
      acc[rt] = __builtin_amdgcn_mfma_f32_16x16x32_f16(af, bf, acc[rt], 0, 0, 0);
    }
  }
#pragma unroll
  for (int rt = 0; rt < 4; ++rt) {
    const int gr = mtile * 64 + rt * 16 + quad * 4;
    const int tc = ntile * 64 + wave * 16 + l16;
    const float bot = bo[tc];
#pragma unroll
    for (int rg = 0; rg < 4; ++rg) {
      const int rr = gr + rg;
      const int bb = rr / 3, oo = rr - bb * 3;
      const float v = acc[rt][rg]
                    + x[(size_t)(bb * 7 + oo) * TT + tc]
                    + w3sh[oo] * bot;
      outY[(size_t)rr * TT + tc] = v;
    }
  }
}

extern "C" void kernel_launch(void* const* d_in, const int* in_sizes, int n_in,
                              void* d_out, int out_size, void* d_ws, size_t ws_size,
                              hipStream_t stream) {
  const float* x  = (const float*)d_in[0];
  const float* W1 = (const float*)d_in[1];
  const float* W2 = (const float*)d_in[2];
  const float* Wq = (const float*)d_in[3];
  const float* bq = (const float*)d_in[4];
  const float* Wk = (const float*)d_in[5];
  const float* bk = (const float*)d_in[6];
  const float* Wv = (const float*)d_in[7];
  const float* bv = (const float*)d_in[8];
  const float* Wo = (const float*)d_in[9];
  const float* bo = (const float*)d_in[10];
  const float* W3 = (const float*)d_in[11];
  float* out = (float*)d_out;

  char* ws = (char*)d_ws;
  float* Xq      = (float*)ws;                  // 192*512  fp32 = 393216 B
  float* Xkv     = (float*)(ws + 393216);       // 256*1024 fp32 = 1048576 B
  _Float16* U    = (_Float16*)(ws + 1441792);   // 192*512  fp16 = 196608 B

  // zero the split-K accumulators (kernel, NOT hipMemsetAsync)
  zero_ws<<<dim3(352), 256, 0, stream>>>((float4*)ws);

  // merged projections: 44 MN-tiles x 32 split-K chunks = 1408 blocks
  proj_gemm<<<dim3(44, 32), 256, 0, stream>>>(x, Wq, Wk, Wv, Xq, Xkv);
  // attention middle -> U (192 x 512 fp16)
  attn_mid<<<dim3(8, BB), 256, 0, stream>>>(Xq, Xkv, W1, W2, W3, bq, bk, bv, U);
  // final projection + residual + bias
  out_gemm<<<dim3(256, 3), 256, 0, stream>>>(U, Wo, x, bo, W3, out);
}